// Round 25
// baseline (108.146 us; speedup 1.0000x reference)
//
#include <hip/hip_runtime.h>
#include <hip/hip_bf16.h>

// Problem: B=2, S=2048, D=1024, H=16, dh=64, THETA=10000
// Pipeline: convert(+cos/sin table) -> QKV GEMM(bf16 MFMA, fused RoPE-from-table,
//           Q pre-scaled by C2, V-transpose epilogue) -> flash attn -> WO GEMM(64x128)
// ws layout: [0,8MB)=xb  [8,16)=wb  [16,24)=Qb  [24,32)=Kb  [32,40)=Vt  [40,48)=Ab
// cos/sin table (2048x32 float2 = 512KB) lives in d_out (fully overwritten by gemm2).
// NOTE 1 (R6): masked-score sentinel -30000.0f, not -1e30 (fp-contract Inf/NaN).
// NOTE 2 (R9): NEVER call sincosf per-element in a GEMM epilogue. Table lookup is safe.
// NOTE 4 (R13): FIXED-m softmax -> no running max, no rescale, additive merge.
// NOTE 8 (R18): gemm XCD swizzle (kept). NOTE 11 (R22): kappa K-row permutation kills
//   the P LDS round-trip (bank conflicts 0). NOTE 12 (R23): causal dead-work skip.
// NOTE 13 (R24): gemm2 64x128 tile -> 512 blocks = 2/CU: independent co-resident
//   blocks overlap each other's barrier drains (-3us). PROVEN mechanism.
// NOTE 14 (R25): same mechanism for attn: P-buffer removal (R22) + reverting pair-
//   rounds to single 64-key rounds shrinks LDS 130K -> 66K -> 2 blocks/CU.
//   launch_bounds(512,4) pins VGPR<=128 to guarantee residency.
// Failed (do not retry): counted-vmcnt graft (R14), T15 interleave (R17), shared-
//   barrier wave scaling (R19), barrier-free global-direct K/V (R20, -76%).

#define S_LEN 2048
#define NEG_SENT -30000.0f

typedef __attribute__((ext_vector_type(8))) short short8;
typedef __attribute__((ext_vector_type(4))) float f32x4;
typedef unsigned int u32;
typedef unsigned short u16;

static __device__ __forceinline__ float bf2f(u16 u) {
  union { u32 i; float f; } v; v.i = ((u32)u) << 16; return v.f;
}
static __device__ __forceinline__ u16 f2bf(float f) {
  union { float f; u32 i; } v; v.f = f;
  u32 u = v.i;
  u32 r = (u + 0x7fffu + ((u >> 16) & 1u)) >> 16;
  return (u16)r;
}
// packed f32x2 -> bf16x2 (RTNE) in one instruction; no builtin on gfx950
static __device__ __forceinline__ u32 cvtpk(float a, float b) {
  u32 r;
  asm("v_cvt_pk_bf16_f32 %0, %1, %2" : "=v"(r) : "v"(a), "v"(b));
  return r;
}

static __device__ __forceinline__ void glds16(const void* g, void* l) {
  __builtin_amdgcn_global_load_lds((const __attribute__((address_space(1))) u32*)g,
                                   (__attribute__((address_space(3))) u32*)l, 16, 0, 0);
}

// ---------------- convert fp32 -> bf16 + build RoPE cos/sin table ----------------
__global__ void convert_kernel(const float* __restrict__ x, const float* __restrict__ wq,
                               const float* __restrict__ wk, const float* __restrict__ wv,
                               const float* __restrict__ wo, const int* __restrict__ pos,
                               u16* __restrict__ xb, u16* __restrict__ wb,
                               float2* __restrict__ tab) {
  const int stride = gridDim.x * blockDim.x;
  for (int i = blockIdx.x * blockDim.x + threadIdx.x; i < 2162688; i += stride) {
    if (i >= 2097152) {
      int e = i - 2097152;  // [0, 65536): s = e>>5, ip = e&31
      int s = e >> 5, ip = e & 31;
      float p = (float)pos[s];
      float ang = p * __builtin_exp2f((float)ip * -0.41524101186f);
      float sn, cs;
      sincosf(ang, &sn, &cs);
      tab[e] = make_float2(cs, sn);
      continue;
    }
    const float* src; u16* dst; int off;
    if (i < 1048576) { src = x; dst = xb; off = i; }
    else {
      int j = i - 1048576;
      int widx = j >> 18;            // 262144 float4 per weight
      off = j & 262143;
      src = (widx == 0) ? wq : (widx == 1) ? wk : (widx == 2) ? wv : wo;
      dst = wb + (size_t)widx * 1048576;
    }
    float4 v = ((const float4*)src)[off];
    ushort4 o;
    o.x = f2bf(v.x); o.y = f2bf(v.y); o.z = f2bf(v.z); o.w = f2bf(v.w);
    ((ushort4*)dst)[off] = o;
  }
}

// ---------------- GEMM1: C = A(MxK) * B(NxK)^T, bf16 in, 128x128 tile ----------------
// XCD-pinned swizzle (NOTE 8). QKV fused epilogues: Q scaled+RoPE, K RoPE, V transpose.
__global__ __launch_bounds__(256, 2) void gemm_qkv(const u16* __restrict__ A,
                                                   const u16* __restrict__ B,
                                                   u16* __restrict__ o0, u16* __restrict__ o1,
                                                   u16* __restrict__ o2,
                                                   const float2* __restrict__ tab, int K) {
  __shared__ __align__(16) u16 AsBs[2 * 128 * 64];  // As | Bs (contiguous 32KB)
  u16* const As = AsBs;
  u16* const Bs = AsBs + 128 * 64;
  const int tid = threadIdx.x, w = tid >> 6, l = tid & 63, l15 = l & 15, l4 = l >> 4;
  const int wr = w >> 1, wc = w & 1;
  const int lid = blockIdx.y * gridDim.x + blockIdx.x;
  const int xcd = lid & 7;
  const int jj2 = lid >> 3;
  const int mrows = gridDim.y >> 3;
  const int m0 = (xcd * mrows + jj2 / gridDim.x) << 7;
  const int n0 = (jj2 % gridDim.x) << 7;
  const int r = tid >> 3;
  const int swcol = ((tid & 7) << 4) ^ ((r & 7) << 4);
  const char* Ag = (const char*)A + (((size_t)(m0 + r) * K) << 1) + swcol;
  const char* Bg = (const char*)B + (((size_t)(n0 + r) * K) << 1) + swcol;
  char* AsW = (char*)As + (w << 10);
  char* BsW = (char*)Bs + (w << 10);
  const size_t rowskip = ((size_t)32 * K) << 1;
  f32x4 acc[4][4] = {};
  for (int k0 = 0; k0 < K; k0 += 64) {
    __syncthreads();
    const size_t kb = (size_t)k0 << 1;
#pragma unroll
    for (int i = 0; i < 4; i++) {
      glds16(Ag + kb + (size_t)i * rowskip, AsW + i * 4096);
      glds16(Bg + kb + (size_t)i * rowskip, BsW + i * 4096);
    }
    __syncthreads();
#pragma unroll
    for (int kk = 0; kk < 2; kk++) {
      short8 a[4], b[4];
#pragma unroll
      for (int m = 0; m < 4; m++) {
        int row = (wr << 6) + (m << 4) + l15;
        a[m] = *(const short8*)((const char*)As + row * 128 +
                                (((kk << 6) + (l4 << 4)) ^ ((row & 7) << 4)));
      }
#pragma unroll
      for (int n = 0; n < 4; n++) {
        int row = (wc << 6) + (n << 4) + l15;
        b[n] = *(const short8*)((const char*)Bs + row * 128 +
                                (((kk << 6) + (l4 << 4)) ^ ((row & 7) << 4)));
      }
#pragma unroll
      for (int m = 0; m < 4; m++)
#pragma unroll
        for (int n = 0; n < 4; n++)
          acc[m][n] = __builtin_amdgcn_mfma_f32_16x16x32_bf16(a[m], b[n], acc[m][n], 0, 0, 0);
    }
  }
  // ---- epilogue ----
  if (n0 >= 2048) {
    // V: LDS transpose (T[s][d], XOR-swizzled column) then coalesced 128B writes
    __syncthreads();
    u16* T = AsBs;  // 128 x 128 u16 = 32KB
#pragma unroll
    for (int m = 0; m < 4; m++)
#pragma unroll
      for (int n = 0; n < 4; n++) {
        int ct = (wc << 6) + (n << 4) + l15;
#pragma unroll
        for (int j = 0; j < 4; j++) {
          int rt = (wr << 6) + (m << 4) + (l4 << 2) + j;
          T[rt * 128 + (ct ^ (((rt >> 6) & 1) << 1))] = f2bf(acc[m][n][j]);
        }
      }
    __syncthreads();
    const int d = tid >> 1, sh = tid & 1;
    const int dr = d ^ (sh << 1);  // read-side column swizzle (matches write)
    const int bb = m0 >> 11;
    const int colv = (n0 & 1023) + d;
    const int row = (((bb << 4) | (colv >> 6)) << 6) | (colv & 63);
    u16* dst = o2 + ((size_t)row << 11) + (m0 & (S_LEN - 1)) + (sh << 6);
#pragma unroll
    for (int k8 = 0; k8 < 8; k8++) {
      u16 tmp[8];
#pragma unroll
      for (int e = 0; e < 8; e++) tmp[e] = T[((sh << 6) + (k8 << 3) + e) * 128 + dr];
      *(uint4*)(dst + (k8 << 3)) = *(const uint4*)tmp;
    }
    return;
  }
#pragma unroll
  for (int m = 0; m < 4; m++) {
    int grow_b = m0 + (wr << 6) + (m << 4) + (l4 << 2);
#pragma unroll
    for (int n = 0; n < 4; n++) {
      int gcol = n0 + (wc << 6) + (n << 4) + l15;
      // Q or K: RoPE from table; Q additionally pre-scaled by C2.
      const float qscale = (gcol < 1024) ? 0.125f * 1.44269504089f : 1.f;
      u16* base = (gcol < 1024) ? o0 : o1;
      const int col = gcol & 1023;
      const int d = col & 63;
      const float sgn = (d & 1) ? 1.f : -1.f;
      const int ip = d >> 1;
#pragma unroll
      for (int j = 0; j < 4; j++) {
        int grow = grow_b + j;
        float v = acc[m][n][j] * qscale;
        float pv = __shfl_xor(v, 1, 64);
        float2 cssn = tab[((grow & (S_LEN - 1)) << 5) + ip];
        base[((size_t)grow << 10) + col] = f2bf(v * cssn.x + pv * cssn.y * sgn);
      }
    }
  }
}

// ---------------- GEMM2: C = A(MxK) * B(NxK)^T, 64x128 tile, f32 out (NOTE 13) -------
__global__ __launch_bounds__(256, 2) void gemm_wo(const u16* __restrict__ A,
                                                  const u16* __restrict__ B,
                                                  float* __restrict__ oF, int K) {
  __shared__ __align__(16) u16 AsBs[(64 + 128) * 64];  // 24KB
  u16* const As = AsBs;
  u16* const Bs = AsBs + 64 * 64;
  const int tid = threadIdx.x, w = tid >> 6, l = tid & 63, l15 = l & 15, l4 = l >> 4;
  const int wr = w >> 1, wc = w & 1;
  const int lid = blockIdx.y * gridDim.x + blockIdx.x;
  const int xcd = lid & 7;
  const int jj2 = lid >> 3;
  const int mrows = gridDim.y >> 3;
  const int m0 = (xcd * mrows + jj2 / gridDim.x) << 6;
  const int n0 = (jj2 % gridDim.x) << 7;
  const int r = tid >> 3;
  const int swcol = ((tid & 7) << 4) ^ ((r & 7) << 4);
  const char* Ag = (const char*)A + (((size_t)(m0 + r) * K) << 1) + swcol;
  const char* Bg = (const char*)B + (((size_t)(n0 + r) * K) << 1) + swcol;
  char* AsW = (char*)As + (w << 10);
  char* BsW = (char*)Bs + (w << 10);
  const size_t rowskip = ((size_t)32 * K) << 1;
  f32x4 acc[2][4] = {};
  for (int k0 = 0; k0 < K; k0 += 64) {
    __syncthreads();
    const size_t kb = (size_t)k0 << 1;
    glds16(Ag + kb, AsW);
    glds16(Ag + kb + rowskip, AsW + 4096);
#pragma unroll
    for (int i = 0; i < 4; i++)
      glds16(Bg + kb + (size_t)i * rowskip, BsW + i * 4096);
    __syncthreads();
#pragma unroll
    for (int kk = 0; kk < 2; kk++) {
      short8 a[2], b[4];
#pragma unroll
      for (int m = 0; m < 2; m++) {
        int row = (wr << 5) + (m << 4) + l15;
        a[m] = *(const short8*)((const char*)As + row * 128 +
                                (((kk << 6) + (l4 << 4)) ^ ((row & 7) << 4)));
      }
#pragma unroll
      for (int n = 0; n < 4; n++) {
        int row = (wc << 6) + (n << 4) + l15;
        b[n] = *(const short8*)((const char*)Bs + row * 128 +
                                (((kk << 6) + (l4 << 4)) ^ ((row & 7) << 4)));
      }
#pragma unroll
      for (int m = 0; m < 2; m++)
#pragma unroll
        for (int n = 0; n < 4; n++)
          acc[m][n] = __builtin_amdgcn_mfma_f32_16x16x32_bf16(a[m], b[n], acc[m][n], 0, 0, 0);
    }
  }
#pragma unroll
  for (int m = 0; m < 2; m++) {
    int grow_b = m0 + (wr << 5) + (m << 4) + (l4 << 2);
#pragma unroll
    for (int n = 0; n < 4; n++) {
      int gcol = n0 + (wc << 6) + (n << 4) + l15;
#pragma unroll
      for (int j = 0; j < 4; j++)
        oF[((size_t)(grow_b + j) << 10) + gcol] = acc[m][n][j];
    }
  }
}

// ---------------- flash attention (causal), swapped-QK, split-K, FIXED-m ----------------
// 256 blocks x 512 threads (8 waves), 66KB LDS -> 2 blocks/CU (NOTE 14). Block i:
// xcd=i&7, slot=i>>3, bh=((slot>>3)<<3)|xcd, p=slot&7. q-tiles p and 15-p SEQUENTIALLY.
// grp0 even 64-key subtiles, grp1 odd; kappa K-rows (NOTE 11); dead-work skip (NOTE 12);
// additive merge (NOTE 4). LDS: grp g K dbuf [g*32K,+16K) V dbuf [+16K,+32K); lMrg @64K.
__global__ __launch_bounds__(512, 4) void attn_kernel(const u16* __restrict__ Q,
                                                      const u16* __restrict__ K,
                                                      const u16* __restrict__ Vt,
                                                      u16* __restrict__ O) {
  extern __shared__ __align__(16) char smem[];
  const int tid = threadIdx.x, w = tid >> 6, l = tid & 63, l15 = l & 15, g = l >> 4;
  const int grp = w >> 2, w4 = w & 3;
  const int i = blockIdx.x;
  const int xcd = i & 7, slot = i >> 3;
  const int bh = ((slot >> 3) << 3) | xcd;
  const int p = slot & 7;
  const int b = bh >> 4, h = bh & 15;
  const int swz = (l15 & 7) << 4;

  // staging sources (per-group 256 threads; pre-swizzled global cols -> linear LDS)
  const int gt = tid & 255;
  const int r = gt >> 3;
  const int kr = ((r & 28) << 1) | (r & 3);  // kappa(r): K-row permutation (NOTE 11)
  const int swc = ((gt & 7) << 4) ^ ((r & 7) << 4);
  const char* Kg = (const char*)K + ((size_t)(b * S_LEN + kr) << 11) + (h << 7) + swc;
  const char* Vg = (const char*)Vt + ((size_t)((bh << 6) + r) << 12) + swc;
  char* const KsG = smem + (grp << 15);          // K dbuf 2 x 8KB
  char* const VsG = smem + (grp << 15) + 16384;  // V dbuf 2 x 8KB
  float* const oMrg = (float*)smem;              // merge area (reuses grp0 K/V, 32KB)
  float* const lMrg = (float*)(smem + 65536);    // l merge (2KB)

  // stage 64-key subtile T into dbuf BSEL. K LDS rows {r, r+32} <- keys T*64+{kr, kr+4}
  // (kappa); V d-rows {r, r+32} <- cols T*64.. (linear).
#define STAGE(T, BSEL)                                              \
  do {                                                              \
    char* kd = KsG + ((BSEL) << 13) + (w4 << 10);                   \
    char* vd = VsG + ((BSEL) << 13) + (w4 << 10);                   \
    const char* ks = Kg + ((size_t)(T) << 17);                      \
    const char* vs = Vg + ((T) << 7);                               \
    glds16(ks, kd);                                                 \
    glds16(ks + (4 << 11), kd + 4096);                              \
    glds16(vs, vd);                                                 \
    glds16(vs + ((size_t)32 << 12), vd + 4096);                     \
  } while (0)

  // ---- one q-tile (qt): single-subtile rounds + additive merge + output ----
  auto run_qt = [&](int qt) {
    const int q0 = qt << 7;
    const int nt = (qt + 1) << 1;  // 64-key subtiles
    const int nr = qt + 1;         // rounds per group (group g takes t = 2rr+g)

    short8 aQ[2][2];
    {
      const int qrow0 = q0 + (w4 << 5) + l15;
      const u16* qp = Q + (((size_t)(b * S_LEN + qrow0)) << 10) + (h << 6) + (g << 3);
      aQ[0][0] = *(const short8*)qp;
      aQ[0][1] = *(const short8*)(qp + 32);
      aQ[1][0] = *(const short8*)(qp + (16 << 10));
      aQ[1][1] = *(const short8*)(qp + (16 << 10) + 32);
    }
    f32x4 o[2][4] = {};
    float l_r[2] = {0.f, 0.f};

    // one 64-key subtile: QK^T (Q pre-scaled), mask (kappa keys), P=exp2(s), PV.
    // aP fragments built IN REGISTER from cvtpk outputs (NOTE 11).
    auto subtile = [&](int t, const char* Kbuf, const char* Vbuf, bool domask) {
      f32x4 s[2][4] = {};
#pragma unroll
      for (int kk = 0; kk < 2; ++kk) {
        short8 aK[4];
#pragma unroll
        for (int n = 0; n < 4; ++n) {
          int row = (n << 4) + l15;
          aK[n] = *(const short8*)(Kbuf + row * 128 + (((kk << 6) + (g << 4)) ^ swz));
        }
        __builtin_amdgcn_s_setprio(1);
#pragma unroll
        for (int n = 0; n < 4; ++n) {
          s[0][n] = __builtin_amdgcn_mfma_f32_16x16x32_bf16(aK[n], aQ[0][kk], s[0][n], 0, 0, 0);
          s[1][n] = __builtin_amdgcn_mfma_f32_16x16x32_bf16(aK[n], aQ[1][kk], s[1][n], 0, 0, 0);
        }
        __builtin_amdgcn_s_setprio(0);
      }
      if (domask) {
#pragma unroll
        for (int qs = 0; qs < 2; ++qs) {
          int qg = q0 + (w4 << 5) + (qs << 4) + l15;
#pragma unroll
          for (int n = 0; n < 4; ++n)
#pragma unroll
            for (int jj = 0; jj < 4; ++jj) {
              int key = (t << 6) + ((n & 1) << 5) + (g << 3) + ((n >> 1) << 2) + jj;
              if (key > qg) s[qs][n][jj] = NEG_SENT;
            }
        }
      }
      short8 aP[2][2];
#pragma unroll
      for (int qs = 0; qs < 2; ++qs) {
        float p_[4][4];
        float rs = 0.f;
#pragma unroll
        for (int n = 0; n < 4; ++n) {
#pragma unroll
          for (int jj = 0; jj < 4; ++jj) {
            p_[n][jj] = __builtin_exp2f(s[qs][n][jj]);
            rs += p_[n][jj];
          }
        }
        l_r[qs] += rs;
#pragma unroll
        for (int kk = 0; kk < 2; ++kk) {
          union { u32 u[4]; short8 v; } wd;
#pragma unroll
          for (int wi = 0; wi < 4; ++wi) {
            const int nw = ((wi >> 1) << 1) | kk;
            wd.u[wi] = cvtpk(p_[nw][(wi & 1) * 2], p_[nw][(wi & 1) * 2 + 1]);
          }
          aP[qs][kk] = wd.v;
        }
      }
#pragma unroll
      for (int kk = 0; kk < 2; ++kk) {
        int co = (kk << 6) + (g << 4);
        __builtin_amdgcn_s_setprio(1);
#pragma unroll
        for (int nd = 0; nd < 4; ++nd) {
          int row = (nd << 4) + l15;
          short8 bV = *(const short8*)(Vbuf + row * 128 + (co ^ swz));
          o[0][nd] = __builtin_amdgcn_mfma_f32_16x16x32_bf16(aP[0][kk], bV, o[0][nd], 0, 0, 0);
          o[1][nd] = __builtin_amdgcn_mfma_f32_16x16x32_bf16(aP[1][kk], bV, o[1][nd], 0, 0, 0);
        }
        __builtin_amdgcn_s_setprio(0);
      }
    };

    if (grp < nt) STAGE(grp, 0);
    __syncthreads();

    for (int rr = 0; rr < nr; ++rr) {
      const int bsel = rr & 1;
      const int t = 2 * rr + grp;
      if (t + 2 < nt) STAGE(t + 2, bsel ^ 1);
      {
        const char* Kbuf = KsG + (bsel << 13);
        const char* Vbuf = VsG + (bsel << 13);
        const bool dm = (t >= nt - 2);
        const bool lowW = (w4 < 2);  // wave-uniform (NOTE 12)
        if (grp == 0) {
          // even subtile (diag first half): mask only for low waves on the diagonal
          subtile(t, Kbuf, Vbuf, dm && lowW);
        } else {
          // odd subtile (diag second half): fully masked for low waves -> skip
          if (!(dm && lowW)) subtile(t, Kbuf, Vbuf, dm);
        }
      }
      __syncthreads();
    }

    // ---- additive split-K merge: group 1 publishes, group 0 adds + normalizes ----
    if (grp == 1) {
      float* ob = oMrg + (w4 << 11);
#pragma unroll
      for (int qs = 0; qs < 2; ++qs)
#pragma unroll
        for (int nd = 0; nd < 4; ++nd)
          *(f32x4*)(ob + (((qs << 2) | nd) << 8) + (l << 2)) = o[qs][nd];
      float* lb = lMrg + (w4 << 7);
      lb[l] = l_r[0];
      lb[64 + l] = l_r[1];
    }
    __syncthreads();
    if (grp == 0) {
      float* ob = oMrg + (w4 << 11);
      float* lb = lMrg + (w4 << 7);
#pragma unroll
      for (int qs = 0; qs < 2; ++qs) {
        float lsum = l_r[qs] + lb[(qs << 6) + l];
        lsum += __shfl_xor(lsum, 16);
        lsum += __shfl_xor(lsum, 32);
        float linv = 1.f / lsum;
        f32x4 oB[4];
#pragma unroll
        for (int nd = 0; nd < 4; ++nd)
          oB[nd] = *(const f32x4*)(ob + (((qs << 2) | nd) << 8) + (l << 2));
#pragma unroll
        for (int jj = 0; jj < 4; ++jj) {
          float lo = __shfl(linv, (g << 2) + jj, 16);
          int qg = q0 + (w4 << 5) + (qs << 4) + (g << 2) + jj;
          u16* orow = O + (((size_t)(b * S_LEN + qg)) << 10) + (h << 6) + l15;
#pragma unroll
          for (int nd = 0; nd < 4; ++nd)
            orow[nd << 4] = f2bf((o[qs][nd][jj] + oB[nd][jj]) * lo);
        }
      }
    }
    __syncthreads();  // protect merge area before next q-tile's STAGE
  };

  run_qt(p);
  run_qt(15 - p);
#undef STAGE
}

extern "C" void kernel_launch(void* const* d_in, const int* in_sizes, int n_in,
                              void* d_out, int out_size, void* d_ws, size_t ws_size,
                              hipStream_t stream) {
  (void)in_sizes; (void)n_in; (void)out_size; (void)ws_size;
  const float* x = (const float*)d_in[0];
  const float* wq = (const float*)d_in[1];
  const float* wk = (const float*)d_in[2];
  const float* wv = (const float*)d_in[3];
  const float* wo = (const float*)d_in[4];
  const int* pos = (const int*)d_in[5];
  char* ws = (char*)d_ws;
  u16* xb = (u16*)ws;
  u16* wb = (u16*)(ws + ((size_t)8 << 20));
  u16* Qb = (u16*)(ws + ((size_t)16 << 20));
  u16* Kb = (u16*)(ws + ((size_t)24 << 20));
  u16* Vtg = (u16*)(ws + ((size_t)32 << 20));
  u16* Ab = (u16*)(ws + ((size_t)40 << 20));
  float* out = (float*)d_out;
  float2* tab = (float2*)d_out;  // 512KB table; gemm2 overwrites d_out afterwards

  convert_kernel<<<2112, 256, 0, stream>>>(x, wq, wk, wv, wo, pos, xb, wb, tab);
  dim3 g1(24, 32);
  gemm_qkv<<<g1, 256, 0, stream>>>(xb, wb, Qb, Kb, Vtg, tab, 1024);
  attn_kernel<<<256, 512, 67584, stream>>>(Qb, Kb, Vtg, Ab);
  dim3 g3(8, 64);
  gemm_wo<<<g3, 256, 0, stream>>>(Ab, wb + (size_t)3 * 1048576, out, 1024);
}

// Round 26
// 97.506 us; speedup vs baseline: 1.1091x; 1.1091x over previous
//
#include <hip/hip_runtime.h>
#include <hip/hip_bf16.h>

// Problem: B=2, S=2048, D=1024, H=16, dh=64, THETA=10000
// Pipeline: convert(+cos/sin table) -> QKV GEMM(bf16 MFMA, fused RoPE-from-table,
//           Q pre-scaled by C2, V-transpose epilogue) -> flash attn -> WO GEMM(64x128)
// ws layout: [0,8MB)=xb  [8,16)=wb  [16,24)=Qb  [24,32)=Kb  [32,40)=Vt  [40,48)=Ab
// cos/sin table (2048x32 float2 = 512KB) lives in d_out (fully overwritten by gemm2).
// NOTE 1 (R6): masked-score sentinel -30000.0f, not -1e30 (fp-contract Inf/NaN).
// NOTE 2 (R9): NEVER call sincosf per-element in a GEMM epilogue. Table lookup is safe.
// NOTE 4 (R13): FIXED-m softmax -> no running max, no rescale, additive merge.
// NOTE 6 (R16): Q pre-scaled by C2; 128-key pair-rounds.
// NOTE 8 (R18): gemm XCD swizzle (kept). NOTE 11 (R22): kappa K-row permutation kills
//   the P LDS round-trip (bank conflicts 0). NOTE 12 (R23): causal dead-work skip.
// NOTE 13 (R24): gemm2 64x128 tile -> 512 blocks = 2/CU: independent co-resident
//   blocks overlap each other's barrier drains (-3us).
// NOTE 15 (R25): attn 2-blocks/CU port REGRESSED (-30%): occupancy didn't rise, VGPR
//   cap to 64 + doubled barrier count dominated. Reverted; this file = R24 (97.56us).
// Failed (do not retry): counted-vmcnt graft (R14), T15 interleave (R17), shared-
//   barrier wave scaling (R19), barrier-free global-direct K/V (R20), attn 2/CU (R25).

#define S_LEN 2048
#define NEG_SENT -30000.0f

typedef __attribute__((ext_vector_type(8))) short short8;
typedef __attribute__((ext_vector_type(4))) float f32x4;
typedef unsigned int u32;
typedef unsigned short u16;

static __device__ __forceinline__ float bf2f(u16 u) {
  union { u32 i; float f; } v; v.i = ((u32)u) << 16; return v.f;
}
static __device__ __forceinline__ u16 f2bf(float f) {
  union { float f; u32 i; } v; v.f = f;
  u32 u = v.i;
  u32 r = (u + 0x7fffu + ((u >> 16) & 1u)) >> 16;
  return (u16)r;
}
// packed f32x2 -> bf16x2 (RTNE) in one instruction; no builtin on gfx950
static __device__ __forceinline__ u32 cvtpk(float a, float b) {
  u32 r;
  asm("v_cvt_pk_bf16_f32 %0, %1, %2" : "=v"(r) : "v"(a), "v"(b));
  return r;
}

static __device__ __forceinline__ void glds16(const void* g, void* l) {
  __builtin_amdgcn_global_load_lds((const __attribute__((address_space(1))) u32*)g,
                                   (__attribute__((address_space(3))) u32*)l, 16, 0, 0);
}

// ---------------- convert fp32 -> bf16 + build RoPE cos/sin table ----------------
__global__ void convert_kernel(const float* __restrict__ x, const float* __restrict__ wq,
                               const float* __restrict__ wk, const float* __restrict__ wv,
                               const float* __restrict__ wo, const int* __restrict__ pos,
                               u16* __restrict__ xb, u16* __restrict__ wb,
                               float2* __restrict__ tab) {
  const int stride = gridDim.x * blockDim.x;
  for (int i = blockIdx.x * blockDim.x + threadIdx.x; i < 2162688; i += stride) {
    if (i >= 2097152) {
      int e = i - 2097152;  // [0, 65536): s = e>>5, ip = e&31
      int s = e >> 5, ip = e & 31;
      float p = (float)pos[s];
      float ang = p * __builtin_exp2f((float)ip * -0.41524101186f);
      float sn, cs;
      sincosf(ang, &sn, &cs);
      tab[e] = make_float2(cs, sn);
      continue;
    }
    const float* src; u16* dst; int off;
    if (i < 1048576) { src = x; dst = xb; off = i; }
    else {
      int j = i - 1048576;
      int widx = j >> 18;            // 262144 float4 per weight
      off = j & 262143;
      src = (widx == 0) ? wq : (widx == 1) ? wk : (widx == 2) ? wv : wo;
      dst = wb + (size_t)widx * 1048576;
    }
    float4 v = ((const float4*)src)[off];
    ushort4 o;
    o.x = f2bf(v.x); o.y = f2bf(v.y); o.z = f2bf(v.z); o.w = f2bf(v.w);
    ((ushort4*)dst)[off] = o;
  }
}

// ---------------- GEMM1: C = A(MxK) * B(NxK)^T, bf16 in, 128x128 tile ----------------
// XCD-pinned swizzle (NOTE 8). QKV fused epilogues: Q scaled+RoPE, K RoPE, V transpose.
__global__ __launch_bounds__(256, 2) void gemm_qkv(const u16* __restrict__ A,
                                                   const u16* __restrict__ B,
                                                   u16* __restrict__ o0, u16* __restrict__ o1,
                                                   u16* __restrict__ o2,
                                                   const float2* __restrict__ tab, int K) {
  __shared__ __align__(16) u16 AsBs[2 * 128 * 64];  // As | Bs (contiguous 32KB)
  u16* const As = AsBs;
  u16* const Bs = AsBs + 128 * 64;
  const int tid = threadIdx.x, w = tid >> 6, l = tid & 63, l15 = l & 15, l4 = l >> 4;
  const int wr = w >> 1, wc = w & 1;
  const int lid = blockIdx.y * gridDim.x + blockIdx.x;
  const int xcd = lid & 7;
  const int jj2 = lid >> 3;
  const int mrows = gridDim.y >> 3;
  const int m0 = (xcd * mrows + jj2 / gridDim.x) << 7;
  const int n0 = (jj2 % gridDim.x) << 7;
  const int r = tid >> 3;
  const int swcol = ((tid & 7) << 4) ^ ((r & 7) << 4);
  const char* Ag = (const char*)A + (((size_t)(m0 + r) * K) << 1) + swcol;
  const char* Bg = (const char*)B + (((size_t)(n0 + r) * K) << 1) + swcol;
  char* AsW = (char*)As + (w << 10);
  char* BsW = (char*)Bs + (w << 10);
  const size_t rowskip = ((size_t)32 * K) << 1;
  f32x4 acc[4][4] = {};
  for (int k0 = 0; k0 < K; k0 += 64) {
    __syncthreads();
    const size_t kb = (size_t)k0 << 1;
#pragma unroll
    for (int i = 0; i < 4; i++) {
      glds16(Ag + kb + (size_t)i * rowskip, AsW + i * 4096);
      glds16(Bg + kb + (size_t)i * rowskip, BsW + i * 4096);
    }
    __syncthreads();
#pragma unroll
    for (int kk = 0; kk < 2; kk++) {
      short8 a[4], b[4];
#pragma unroll
      for (int m = 0; m < 4; m++) {
        int row = (wr << 6) + (m << 4) + l15;
        a[m] = *(const short8*)((const char*)As + row * 128 +
                                (((kk << 6) + (l4 << 4)) ^ ((row & 7) << 4)));
      }
#pragma unroll
      for (int n = 0; n < 4; n++) {
        int row = (wc << 6) + (n << 4) + l15;
        b[n] = *(const short8*)((const char*)Bs + row * 128 +
                                (((kk << 6) + (l4 << 4)) ^ ((row & 7) << 4)));
      }
#pragma unroll
      for (int m = 0; m < 4; m++)
#pragma unroll
        for (int n = 0; n < 4; n++)
          acc[m][n] = __builtin_amdgcn_mfma_f32_16x16x32_bf16(a[m], b[n], acc[m][n], 0, 0, 0);
    }
  }
  // ---- epilogue ----
  if (n0 >= 2048) {
    // V: LDS transpose (T[s][d], XOR-swizzled column) then coalesced 128B writes
    __syncthreads();
    u16* T = AsBs;  // 128 x 128 u16 = 32KB
#pragma unroll
    for (int m = 0; m < 4; m++)
#pragma unroll
      for (int n = 0; n < 4; n++) {
        int ct = (wc << 6) + (n << 4) + l15;
#pragma unroll
        for (int j = 0; j < 4; j++) {
          int rt = (wr << 6) + (m << 4) + (l4 << 2) + j;
          T[rt * 128 + (ct ^ (((rt >> 6) & 1) << 1))] = f2bf(acc[m][n][j]);
        }
      }
    __syncthreads();
    const int d = tid >> 1, sh = tid & 1;
    const int dr = d ^ (sh << 1);  // read-side column swizzle (matches write)
    const int bb = m0 >> 11;
    const int colv = (n0 & 1023) + d;
    const int row = (((bb << 4) | (colv >> 6)) << 6) | (colv & 63);
    u16* dst = o2 + ((size_t)row << 11) + (m0 & (S_LEN - 1)) + (sh << 6);
#pragma unroll
    for (int k8 = 0; k8 < 8; k8++) {
      u16 tmp[8];
#pragma unroll
      for (int e = 0; e < 8; e++) tmp[e] = T[((sh << 6) + (k8 << 3) + e) * 128 + dr];
      *(uint4*)(dst + (k8 << 3)) = *(const uint4*)tmp;
    }
    return;
  }
#pragma unroll
  for (int m = 0; m < 4; m++) {
    int grow_b = m0 + (wr << 6) + (m << 4) + (l4 << 2);
#pragma unroll
    for (int n = 0; n < 4; n++) {
      int gcol = n0 + (wc << 6) + (n << 4) + l15;
      // Q or K: RoPE from table; Q additionally pre-scaled by C2 (NOTE 6).
      const float qscale = (gcol < 1024) ? 0.125f * 1.44269504089f : 1.f;
      u16* base = (gcol < 1024) ? o0 : o1;
      const int col = gcol & 1023;
      const int d = col & 63;
      const float sgn = (d & 1) ? 1.f : -1.f;
      const int ip = d >> 1;
#pragma unroll
      for (int j = 0; j < 4; j++) {
        int grow = grow_b + j;
        float v = acc[m][n][j] * qscale;
        float pv = __shfl_xor(v, 1, 64);
        float2 cssn = tab[((grow & (S_LEN - 1)) << 5) + ip];
        base[((size_t)grow << 10) + col] = f2bf(v * cssn.x + pv * cssn.y * sgn);
      }
    }
  }
}

// ---------------- GEMM2: C = A(MxK) * B(NxK)^T, 64x128 tile, f32 out (NOTE 13) -------
// grid (8, 64) = 512 blocks = 2 blocks/CU exact. 4 waves as 2x2: each 32x64 (acc[2][4]).
// LDS 24KB: As 64x64 | Bs 128x64. XCD swizzle: mrows = 64/8 = 8 m-panels per XCD.
__global__ __launch_bounds__(256, 2) void gemm_wo(const u16* __restrict__ A,
                                                  const u16* __restrict__ B,
                                                  float* __restrict__ oF, int K) {
  __shared__ __align__(16) u16 AsBs[(64 + 128) * 64];  // 24KB
  u16* const As = AsBs;
  u16* const Bs = AsBs + 64 * 64;
  const int tid = threadIdx.x, w = tid >> 6, l = tid & 63, l15 = l & 15, l4 = l >> 4;
  const int wr = w >> 1, wc = w & 1;
  const int lid = blockIdx.y * gridDim.x + blockIdx.x;
  const int xcd = lid & 7;
  const int jj2 = lid >> 3;
  const int mrows = gridDim.y >> 3;
  const int m0 = (xcd * mrows + jj2 / gridDim.x) << 6;
  const int n0 = (jj2 % gridDim.x) << 7;
  const int r = tid >> 3;
  const int swcol = ((tid & 7) << 4) ^ ((r & 7) << 4);
  const char* Ag = (const char*)A + (((size_t)(m0 + r) * K) << 1) + swcol;
  const char* Bg = (const char*)B + (((size_t)(n0 + r) * K) << 1) + swcol;
  char* AsW = (char*)As + (w << 10);
  char* BsW = (char*)Bs + (w << 10);
  const size_t rowskip = ((size_t)32 * K) << 1;
  f32x4 acc[2][4] = {};
  for (int k0 = 0; k0 < K; k0 += 64) {
    __syncthreads();
    const size_t kb = (size_t)k0 << 1;
    glds16(Ag + kb, AsW);
    glds16(Ag + kb + rowskip, AsW + 4096);
#pragma unroll
    for (int i = 0; i < 4; i++)
      glds16(Bg + kb + (size_t)i * rowskip, BsW + i * 4096);
    __syncthreads();
#pragma unroll
    for (int kk = 0; kk < 2; kk++) {
      short8 a[2], b[4];
#pragma unroll
      for (int m = 0; m < 2; m++) {
        int row = (wr << 5) + (m << 4) + l15;
        a[m] = *(const short8*)((const char*)As + row * 128 +
                                (((kk << 6) + (l4 << 4)) ^ ((row & 7) << 4)));
      }
#pragma unroll
      for (int n = 0; n < 4; n++) {
        int row = (wc << 6) + (n << 4) + l15;
        b[n] = *(const short8*)((const char*)Bs + row * 128 +
                                (((kk << 6) + (l4 << 4)) ^ ((row & 7) << 4)));
      }
#pragma unroll
      for (int m = 0; m < 2; m++)
#pragma unroll
        for (int n = 0; n < 4; n++)
          acc[m][n] = __builtin_amdgcn_mfma_f32_16x16x32_bf16(a[m], b[n], acc[m][n], 0, 0, 0);
    }
  }
#pragma unroll
  for (int m = 0; m < 2; m++) {
    int grow_b = m0 + (wr << 5) + (m << 4) + (l4 << 2);
#pragma unroll
    for (int n = 0; n < 4; n++) {
      int gcol = n0 + (wc << 6) + (n << 4) + l15;
#pragma unroll
      for (int j = 0; j < 4; j++)
        oF[((size_t)(grow_b + j) << 10) + gcol] = acc[m][n][j];
    }
  }
}

// ---------------- flash attention (causal), swapped-QK, split-K, FIXED-m ----------------
// 256 blocks x 512 threads (8 waves). Block i: xcd=i&7, slot=i>>3, bh=((slot>>3)<<3)|xcd,
// p=slot&7. q-tiles p and 15-p SEQUENTIALLY. grp0 even pairs, grp1 odd pairs of 64-key
// subtiles (128 keys/round). K rows kappa-permuted in LDS (NOTE 11); dead-work skip in
// the final pair (NOTE 12). Partials merged by ADDITION (fixed m, NOTE 4).
// LDS: grp0 K[0,32K) V[32,64K); grp1 K[64,96K) V[96,128K); lMrg [128K,130K).
__global__ __launch_bounds__(512, 1) void attn_kernel(const u16* __restrict__ Q,
                                                      const u16* __restrict__ K,
                                                      const u16* __restrict__ Vt,
                                                      u16* __restrict__ O) {
  extern __shared__ __align__(16) char smem[];
  const int tid = threadIdx.x, w = tid >> 6, l = tid & 63, l15 = l & 15, g = l >> 4;
  const int grp = w >> 2, w4 = w & 3;
  const int i = blockIdx.x;
  const int xcd = i & 7, slot = i >> 3;
  const int bh = ((slot >> 3) << 3) | xcd;
  const int p = slot & 7;
  const int b = bh >> 4, h = bh & 15;
  const int swz = (l15 & 7) << 4;

  // staging sources (per-group 256 threads; pre-swizzled global cols -> linear LDS)
  const int gt = tid & 255;
  const int r = gt >> 3;
  const int kr = ((r & 28) << 1) | (r & 3);  // kappa(r): K-row permutation (NOTE 11)
  const int swc = ((gt & 7) << 4) ^ ((r & 7) << 4);
  const char* Kg = (const char*)K + ((size_t)(b * S_LEN + kr) << 11) + (h << 7) + swc;
  const char* Vg = (const char*)Vt + ((size_t)((bh << 6) + r) << 12) + swc;
  char* const KsG = smem + (grp << 16);          // K 2 round-bufs x 16KB
  char* const VsG = smem + (grp << 16) + 32768;  // V 2 round-bufs x 16KB
  float* const oMrg = (float*)smem;              // merge area (reuses grp0 K)
  float* const lMrg = (float*)(smem + 131072);   // l merge (2KB)

  // stage pair PI (keys PI*128..+127) into round-buffer BSEL; K rows kappa-permuted:
  // LDS rows {r, r+32, r+64, r+96} <- global rows PI*128 + {kr, kr+4, 64+kr, 68+kr}
#define STAGE2(PI, BSEL)                                            \
  do {                                                              \
    char* kd = KsG + ((BSEL) << 14) + (w4 << 10);                   \
    char* vd = VsG + ((BSEL) << 14) + (w4 << 10);                   \
    const char* ks = Kg + ((size_t)(PI) << 18);                     \
    const char* vs = Vg + ((PI) << 8);                              \
    glds16(ks, kd);                                                 \
    glds16(ks + (4 << 11), kd + 4096);                              \
    glds16(ks + (64 << 11), kd + 8192);                             \
    glds16(ks + (68 << 11), kd + 12288);                            \
    glds16(vs, vd);                                                 \
    glds16(vs + ((size_t)32 << 12), vd + 4096);                     \
    glds16(vs + 128, vd + 8192);                                    \
    glds16(vs + 128 + ((size_t)32 << 12), vd + 12288);              \
  } while (0)

  // ---- one q-tile (qt): pair-round key loop + additive merge + output ----
  auto run_qt = [&](int qt) {
    const int q0 = qt << 7;
    const int nr = (qt + 2) >> 1;  // pair-rounds (max over groups)

    short8 aQ[2][2];
    {
      const int qrow0 = q0 + (w4 << 5) + l15;
      const u16* qp = Q + (((size_t)(b * S_LEN + qrow0)) << 10) + (h << 6) + (g << 3);
      aQ[0][0] = *(const short8*)qp;
      aQ[0][1] = *(const short8*)(qp + 32);
      aQ[1][0] = *(const short8*)(qp + (16 << 10));
      aQ[1][1] = *(const short8*)(qp + (16 << 10) + 32);
    }
    f32x4 o[2][4] = {};
    float l_r[2] = {0.f, 0.f};

    // one 64-key subtile: QK^T (Q pre-scaled), mask (kappa keys), P=exp2(s), PV.
    // aP fragments built IN REGISTER from cvtpk outputs (NOTE 11).
    auto subtile = [&](int t, const char* Kbuf, const char* Vbuf, bool domask) {
      f32x4 s[2][4] = {};
#pragma unroll
      for (int kk = 0; kk < 2; ++kk) {
        short8 aK[4];
#pragma unroll
        for (int n = 0; n < 4; ++n) {
          int row = (n << 4) + l15;
          aK[n] = *(const short8*)(Kbuf + row * 128 + (((kk << 6) + (g << 4)) ^ swz));
        }
        __builtin_amdgcn_s_setprio(1);
#pragma unroll
        for (int n = 0; n < 4; ++n) {
          s[0][n] = __builtin_amdgcn_mfma_f32_16x16x32_bf16(aK[n], aQ[0][kk], s[0][n], 0, 0, 0);
          s[1][n] = __builtin_amdgcn_mfma_f32_16x16x32_bf16(aK[n], aQ[1][kk], s[1][n], 0, 0, 0);
        }
        __builtin_amdgcn_s_setprio(0);
      }
      if (domask) {
#pragma unroll
        for (int qs = 0; qs < 2; ++qs) {
          int qg = q0 + (w4 << 5) + (qs << 4) + l15;
#pragma unroll
          for (int n = 0; n < 4; ++n)
#pragma unroll
            for (int jj = 0; jj < 4; ++jj) {
              int key = (t << 6) + ((n & 1) << 5) + (g << 3) + ((n >> 1) << 2) + jj;
              if (key > qg) s[qs][n][jj] = NEG_SENT;
            }
        }
      }
      short8 aP[2][2];
#pragma unroll
      for (int qs = 0; qs < 2; ++qs) {
        float p_[4][4];
        float rs = 0.f;
#pragma unroll
        for (int n = 0; n < 4; ++n) {
#pragma unroll
          for (int jj = 0; jj < 4; ++jj) {
            p_[n][jj] = __builtin_exp2f(s[qs][n][jj]);
            rs += p_[n][jj];
          }
        }
        l_r[qs] += rs;
#pragma unroll
        for (int kk = 0; kk < 2; ++kk) {
          union { u32 u[4]; short8 v; } wd;
#pragma unroll
          for (int wi = 0; wi < 4; ++wi) {
            const int nw = ((wi >> 1) << 1) | kk;
            wd.u[wi] = cvtpk(p_[nw][(wi & 1) * 2], p_[nw][(wi & 1) * 2 + 1]);
          }
          aP[qs][kk] = wd.v;
        }
      }
#pragma unroll
      for (int kk = 0; kk < 2; ++kk) {
        int co = (kk << 6) + (g << 4);
        __builtin_amdgcn_s_setprio(1);
#pragma unroll
        for (int nd = 0; nd < 4; ++nd) {
          int row = (nd << 4) + l15;
          short8 bV = *(const short8*)(Vbuf + row * 128 + (co ^ swz));
          o[0][nd] = __builtin_amdgcn_mfma_f32_16x16x32_bf16(aP[0][kk], bV, o[0][nd], 0, 0, 0);
          o[1][nd] = __builtin_amdgcn_mfma_f32_16x16x32_bf16(aP[1][kk], bV, o[1][nd], 0, 0, 0);
        }
        __builtin_amdgcn_s_setprio(0);
      }
    };

    if (grp <= qt) STAGE2(grp, 0);
    __syncthreads();

    for (int rr = 0; rr < nr; ++rr) {
      const int bsel = rr & 1;
      const int pi = 2 * rr + grp;
      if (pi + 2 <= qt) STAGE2(pi + 2, bsel ^ 1);
      if (pi <= qt) {
        const char* Kb0 = KsG + (bsel << 14);
        const char* Vb0 = VsG + (bsel << 14);
        const bool dm = (pi == qt);
        const bool lowW = (w4 < 2);  // wave-uniform (NOTE 12)
        subtile(2 * pi, Kb0, Vb0, dm && lowW);
        if (!(dm && lowW))
          subtile(2 * pi + 1, Kb0 + 8192, Vb0 + 8192, dm);
      }
      __syncthreads();
    }

    // ---- additive split-K merge: group 1 publishes, group 0 adds + normalizes ----
    if (grp == 1) {
      float* ob = oMrg + (w4 << 11);
#pragma unroll
      for (int qs = 0; qs < 2; ++qs)
#pragma unroll
        for (int nd = 0; nd < 4; ++nd)
          *(f32x4*)(ob + (((qs << 2) | nd) << 8) + (l << 2)) = o[qs][nd];
      float* lb = lMrg + (w4 << 7);
      lb[l] = l_r[0];
      lb[64 + l] = l_r[1];
    }
    __syncthreads();
    if (grp == 0) {
      float* ob = oMrg + (w4 << 11);
      float* lb = lMrg + (w4 << 7);
#pragma unroll
      for (int qs = 0; qs < 2; ++qs) {
        float lsum = l_r[qs] + lb[(qs << 6) + l];
        lsum += __shfl_xor(lsum, 16);
        lsum += __shfl_xor(lsum, 32);
        float linv = 1.f / lsum;
        f32x4 oB[4];
#pragma unroll
        for (int nd = 0; nd < 4; ++nd)
          oB[nd] = *(const f32x4*)(ob + (((qs << 2) | nd) << 8) + (l << 2));
#pragma unroll
        for (int jj = 0; jj < 4; ++jj) {
          float lo = __shfl(linv, (g << 2) + jj, 16);
          int qg = q0 + (w4 << 5) + (qs << 4) + (g << 2) + jj;
          u16* orow = O + (((size_t)(b * S_LEN + qg)) << 10) + (h << 6) + l15;
#pragma unroll
          for (int nd = 0; nd < 4; ++nd)
            orow[nd << 4] = f2bf((o[qs][nd][jj] + oB[nd][jj]) * lo);
        }
      }
    }
    __syncthreads();  // protect merge area before next q-tile's STAGE
  };

  run_qt(p);
  run_qt(15 - p);
#undef STAGE2
}

extern "C" void kernel_launch(void* const* d_in, const int* in_sizes, int n_in,
                              void* d_out, int out_size, void* d_ws, size_t ws_size,
                              hipStream_t stream) {
  (void)in_sizes; (void)n_in; (void)out_size; (void)ws_size;
  const float* x = (const float*)d_in[0];
  const float* wq = (const float*)d_in[1];
  const float* wk = (const float*)d_in[2];
  const float* wv = (const float*)d_in[3];
  const float* wo = (const float*)d_in[4];
  const int* pos = (const int*)d_in[5];
  char* ws = (char*)d_ws;
  u16* xb = (u16*)ws;
  u16* wb = (u16*)(ws + ((size_t)8 << 20));
  u16* Qb = (u16*)(ws + ((size_t)16 << 20));
  u16* Kb = (u16*)(ws + ((size_t)24 << 20));
  u16* Vtg = (u16*)(ws + ((size_t)32 << 20));
  u16* Ab = (u16*)(ws + ((size_t)40 << 20));
  float* out = (float*)d_out;
  float2* tab = (float2*)d_out;  // 512KB table; gemm2 overwrites d_out afterwards

  convert_kernel<<<2112, 256, 0, stream>>>(x, wq, wk, wv, wo, pos, xb, wb, tab);
  dim3 g1(24, 32);
  gemm_qkv<<<g1, 256, 0, stream>>>(xb, wb, Qb, Kb, Vtg, tab, 1024);
  attn_kernel<<<256, 512, 135168, stream>>>(Qb, Kb, Vtg, Ab);
  dim3 g3(8, 64);
  gemm_wo<<<g3, 256, 0, stream>>>(Ab, wb + (size_t)3 * 1048576, out, 1024);
}